// Round 1
// 1386.350 us; speedup vs baseline: 1.1649x; 1.1649x over previous
//
#include <hip/hip_runtime.h>
#include <hip/hip_bf16.h>
#include <math.h>

// RWKV-7 TimeMix. R4: DPP row_ror reductions in wkv7 (kill ds_swizzle on the
// serial chain) + 4-wave blocks for L1 dedupe of shared head-streams.
// B=4 T=2048 C=768 H=12 N=64, LAYER_ID=1.

#define B_  4
#define T_  2048
#define C_  768
#define H_  12

typedef __attribute__((ext_vector_type(8))) short bf16x8;
typedef __attribute__((ext_vector_type(4))) float f32x4;

#define GLD16(gsrc, ldst)                                                     \
  __builtin_amdgcn_global_load_lds(                                           \
      (const __attribute__((address_space(1))) void*)(gsrc),                  \
      (__attribute__((address_space(3))) void*)(ldst), 16, 0, 0)

// ---- DPP helpers: sum across each 16-lane DPP row, all-VALU ----
template <int CTRL>
static __device__ __forceinline__ float row_ror_add(float v) {
  int t = __builtin_amdgcn_update_dpp(0, __float_as_int(v), CTRL, 0xF, 0xF, true);
  return v + __int_as_float(t);
}
static __device__ __forceinline__ float row_sum16(float v) {
  v = row_ror_add<0x128>(v);  // row_ror:8
  v = row_ror_add<0x124>(v);  // row_ror:4
  v = row_ror_add<0x122>(v);  // row_ror:2
  v = row_ror_add<0x121>(v);  // row_ror:1
  return v;                   // every lane in the 16-group holds the sum
}

static __device__ __forceinline__ float wave_sum64(float v) {
  v = row_sum16(v);
  v += __shfl_xor(v, 16);
  v += __shfl_xor(v, 32);
  return v;
}

static __device__ __forceinline__ short bf16b(float f) {
  __hip_bfloat16 h = __float2bfloat16(f);
  return *reinterpret_cast<short*>(&h);
}

// ---------------- bf16 MFMA GEMM ----------------
// C[M,N] = A[M,K](bf16) @ Bw[N,K](bf16)^T, fp32 out. 128x128 tile, BK=32.
// 4 waves in 2x2, each wave 64x64 via 4x4 grid of 16x16x32 MFMAs.
__global__ __launch_bounds__(256) void gemm_bf16_k(
    const short* __restrict__ A, const short* __restrict__ Bw,
    float* __restrict__ C, int M, int N, int K) {
  __shared__ short As[128 * 32];
  __shared__ short Bs[128 * 32];
  const int tid = threadIdx.x;
  const int wave = tid >> 6, lane = tid & 63;
  const int m0 = blockIdx.y * 128, n0 = blockIdx.x * 128;
  const int wm = (wave >> 1) * 64, wn = (wave & 1) * 64;
  const int fr = lane & 15, fk = (lane >> 4) * 8;

  f32x4 acc[4][4];
#pragma unroll
  for (int i = 0; i < 4; i++)
#pragma unroll
    for (int j = 0; j < 4; j++) acc[i][j] = (f32x4){0.f, 0.f, 0.f, 0.f};

  // staging map: thread t -> LDS short-offset 8*t == row (t>>2), col (t&3)*8
  const int srow = tid >> 2, scol = (tid & 3) * 8;
  const short* gA = A + (size_t)(m0 + srow) * K + scol;
  const short* gB = Bw + (size_t)(n0 + srow) * K + scol;
  short* lA0 = &As[wave * 512];
  short* lA1 = &As[2048 + wave * 512];
  short* lB0 = &Bs[wave * 512];
  short* lB1 = &Bs[2048 + wave * 512];

  for (int k0 = 0; k0 < K; k0 += 32) {
    GLD16(gA + k0, lA0);
    GLD16(gA + (size_t)64 * K + k0, lA1);
    GLD16(gB + k0, lB0);
    GLD16(gB + (size_t)64 * K + k0, lB1);
    __syncthreads();

    bf16x8 af[4], bf[4];
#pragma unroll
    for (int i = 0; i < 4; i++)
      af[i] = *(const bf16x8*)&As[(wm + i * 16 + fr) * 32 + fk];
#pragma unroll
    for (int j = 0; j < 4; j++)
      bf[j] = *(const bf16x8*)&Bs[(wn + j * 16 + fr) * 32 + fk];
#pragma unroll
    for (int i = 0; i < 4; i++)
#pragma unroll
      for (int j = 0; j < 4; j++)
        acc[i][j] =
            __builtin_amdgcn_mfma_f32_16x16x32_bf16(af[i], bf[j], acc[i][j], 0, 0, 0);
    __syncthreads();
  }

  // C/D layout: col = lane&15, row = (lane>>4)*4 + reg  [m89/m91 verified]
#pragma unroll
  for (int i = 0; i < 4; i++) {
    const int gm = m0 + wm + i * 16 + (lane >> 4) * 4;
#pragma unroll
    for (int j = 0; j < 4; j++) {
      const int gn = n0 + wn + j * 16 + fr;
#pragma unroll
      for (int rix = 0; rix < 4; rix++)
        C[(size_t)(gm + rix) * N + gn] = acc[i][j][rix];
    }
  }
}

// ---------------- fp32 GEMM (small paths) ----------------
enum { EPI_NONE = 0, EPI_TANH, EPI_WDECAY, EPI_SIGBIAS, EPI_SIGMOID, EPI_VMIX };

template <bool MIX, bool BT, int EPI>
__global__ __launch_bounds__(256) void gemm_k(
    const float* __restrict__ A, const float* __restrict__ Bm,
    float* __restrict__ Cc, int M, int N, int K,
    const float* __restrict__ lam, const float* __restrict__ bias,
    const float* __restrict__ ex1, const float* __restrict__ ex2) {
  __shared__ float As[64][20];
  __shared__ float Bs[64][20];
  const int tid = threadIdx.x;
  const int n0 = blockIdx.x * 64;
  const int m0 = blockIdx.y * 64;
  const int tx = tid & 15, ty = tid >> 4;

  float acc[4][4];
#pragma unroll
  for (int i = 0; i < 4; i++)
#pragma unroll
    for (int j = 0; j < 4; j++) acc[i][j] = 0.f;

  const int lm = tid >> 2;
  const int lk4 = (tid & 3) * 4;

  for (int k0 = 0; k0 < K; k0 += 16) {
    {
      const int gm = m0 + lm;
      const float* ap = A + (size_t)gm * K + k0 + lk4;
      float4 xa = *(const float4*)ap;
      if (MIX) {
        float4 xp = make_float4(0.f, 0.f, 0.f, 0.f);
        if ((gm % T_) != 0) xp = *(const float4*)(ap - K);
        const float4 l4 = *(const float4*)(lam + k0 + lk4);
        xa.x += (xp.x - xa.x) * l4.x;
        xa.y += (xp.y - xa.y) * l4.y;
        xa.z += (xp.z - xa.z) * l4.z;
        xa.w += (xp.w - xa.w) * l4.w;
      }
      *(float4*)&As[lm][lk4] = xa;
    }
    if (BT) {
      const int gn = n0 + lm;
      const float4 bv = *(const float4*)(Bm + (size_t)gn * K + k0 + lk4);
      *(float4*)&Bs[lm][lk4] = bv;
    } else {
      const int kl = tid >> 4;
      const int nl = (tid & 15) * 4;
      const float4 bv = *(const float4*)(Bm + (size_t)(k0 + kl) * N + n0 + nl);
      Bs[nl + 0][kl] = bv.x;
      Bs[nl + 1][kl] = bv.y;
      Bs[nl + 2][kl] = bv.z;
      Bs[nl + 3][kl] = bv.w;
    }
    __syncthreads();

#pragma unroll
    for (int kb = 0; kb < 16; kb += 4) {
      float a4[4][4], b4[4][4];
#pragma unroll
      for (int i = 0; i < 4; i++) {
        const float4 t = *(const float4*)&As[ty * 4 + i][kb];
        a4[i][0] = t.x; a4[i][1] = t.y; a4[i][2] = t.z; a4[i][3] = t.w;
      }
#pragma unroll
      for (int j = 0; j < 4; j++) {
        const float4 t = *(const float4*)&Bs[tx * 4 + j][kb];
        b4[j][0] = t.x; b4[j][1] = t.y; b4[j][2] = t.z; b4[j][3] = t.w;
      }
#pragma unroll
      for (int u = 0; u < 4; u++)
#pragma unroll
        for (int i = 0; i < 4; i++)
#pragma unroll
          for (int j = 0; j < 4; j++)
            acc[i][j] = fmaf(a4[i][u], b4[j][u], acc[i][j]);
    }
    __syncthreads();
  }

#pragma unroll
  for (int i = 0; i < 4; i++) {
    const int gm = m0 + ty * 4 + i;
    float res[4];
#pragma unroll
    for (int j = 0; j < 4; j++) {
      const int n = n0 + tx * 4 + j;
      float val = acc[i][j];
      if (EPI == EPI_TANH) {
        val = tanhf(val);
      } else if (EPI == EPI_WDECAY) {
        const float u = bias[n] + val;
        const float sig = 1.f / (1.f + expf(-u));
        val = expf(-0.60653065971263342f * sig);
      } else if (EPI == EPI_SIGBIAS) {
        const float u = bias[n] + val;
        val = 1.f / (1.f + expf(-u));
      } else if (EPI == EPI_SIGMOID) {
        val = 1.f / (1.f + expf(-val));
      } else if (EPI == EPI_VMIX) {
        const float u = bias[n] + val;
        const float sg = 1.f / (1.f + expf(-u));
        const size_t off = (size_t)gm * N + n;
        const float v0v = ex1[off];
        const float vf = ex2[off];
        val = v0v + (vf - v0v) * sg;
      }
      res[j] = val;
    }
    *(float4*)(Cc + (size_t)gm * N + n0 + tx * 4) =
        make_float4(res[0], res[1], res[2], res[3]);
  }
}

// ---------------- mix -> bf16 (3 lambdas) ----------------
__global__ __launch_bounds__(256) void mix3_k(
    const float* __restrict__ x, const float* __restrict__ lr,
    const float* __restrict__ lk, const float* __restrict__ lv,
    short* __restrict__ xr, short* __restrict__ xk, short* __restrict__ xv) {
  const int i = blockIdx.x * 256 + threadIdx.x;  // float4 index
  const int c4 = i % (C_ / 4);
  const int gm = i / (C_ / 4);
  const float4 xa = ((const float4*)x)[i];
  float4 xp = make_float4(0.f, 0.f, 0.f, 0.f);
  if ((gm % T_) != 0) xp = ((const float4*)x)[i - C_ / 4];
  const float4 dx = make_float4(xp.x - xa.x, xp.y - xa.y, xp.z - xa.z, xp.w - xa.w);

  const float4 l1 = ((const float4*)lr)[c4];
  const float4 l2 = ((const float4*)lk)[c4];
  const float4 l3 = ((const float4*)lv)[c4];
  short4 o1 = {bf16b(fmaf(dx.x, l1.x, xa.x)), bf16b(fmaf(dx.y, l1.y, xa.y)),
               bf16b(fmaf(dx.z, l1.z, xa.z)), bf16b(fmaf(dx.w, l1.w, xa.w))};
  short4 o2 = {bf16b(fmaf(dx.x, l2.x, xa.x)), bf16b(fmaf(dx.y, l2.y, xa.y)),
               bf16b(fmaf(dx.z, l2.z, xa.z)), bf16b(fmaf(dx.w, l2.w, xa.w))};
  short4 o3 = {bf16b(fmaf(dx.x, l3.x, xa.x)), bf16b(fmaf(dx.y, l3.y, xa.y)),
               bf16b(fmaf(dx.z, l3.z, xa.z)), bf16b(fmaf(dx.w, l3.w, xa.w))};
  ((short4*)xr)[i] = o1;
  ((short4*)xk)[i] = o2;
  ((short4*)xv)[i] = o3;
}

// ---------------- fp32 -> bf16 convert ----------------
__global__ __launch_bounds__(256) void cvtw_k(const float* __restrict__ in,
                                              short* __restrict__ out, int n4) {
  const int i = blockIdx.x * 256 + threadIdx.x;
  if (i >= n4) return;
  const float4 v = ((const float4*)in)[i];
  short4 o = {bf16b(v.x), bf16b(v.y), bf16b(v.z), bf16b(v.w)};
  ((short4*)out)[i] = o;
}

// ---------------- kk prep ----------------
__global__ __launch_bounds__(256) void kkprep_k(
    const float* __restrict__ k0, const float* __restrict__ a,
    const float* __restrict__ k_k, const float* __restrict__ k_a,
    float* __restrict__ kout, float* __restrict__ z, float* __restrict__ bb) {
  const int wid = threadIdx.x >> 6;
  const int lane = threadIdx.x & 63;
  const size_t hid = (size_t)blockIdx.x * 4 + wid;
  const int h = (int)(hid % H_);
  const size_t idx = hid * 64 + lane;
  const int c = h * 64 + lane;
  const float kv = k0[idx];
  const float av = a[idx];
  const float kk = kv * k_k[c];
  const float ss = wave_sum64(kk * kk);
  const float denom = fmaxf(sqrtf(ss), 1e-12f);
  const float kkn = kk / denom;
  z[idx] = -kkn;
  bb[idx] = kkn * av;
  kout[idx] = kv * (1.f + (av - 1.f) * k_a[c]);
}

// ---------------- WKV-7 recurrence ----------------
// R4: 192 blocks (B*H*4) x 256 threads (4 waves). Each wave owns 4 rows of
// the 64x64 state; 16 lanes/row, 4 cols/lane. All 4 waves read the SAME
// z/w/b/k/r stream addresses -> L1 dedupe. Reductions are DPP row_ror adds
// (VALU) instead of ds_swizzle -> serial chain ~45 cyc/step.
#define PFD 8
__global__ __launch_bounds__(256) void wkv7_k(
    const float* __restrict__ rr, const float* __restrict__ dd,
    const float* __restrict__ kk, const float* __restrict__ vv,
    const float* __restrict__ zz, const float* __restrict__ bbv,
    float* __restrict__ yy) {
  const int blk = blockIdx.x;        // 0..191
  const int bh = blk >> 2;           // 0..47
  const int rq = blk & 3;            // quarter of the rows
  const int b = bh / H_, h = bh % H_;
  const int tid = threadIdx.x;
  const int wave = tid >> 6;
  const int l = tid & 63;
  const int l16 = l & 15;
  const int row = rq * 16 + wave * 4 + (l >> 4);
  const int cb = l16 * 4;

  float S0 = 0.f, S1 = 0.f, S2 = 0.f, S3 = 0.f;
  const size_t base0 = ((size_t)b * T_) * C_ + h * 64;

  float4 wv[PFD], zv[PFD], bv[PFD], kv[PFD], rv[PFD];
  float vval[PFD];
#pragma unroll
  for (int d = 0; d < PFD; d++) {
    const size_t pb = base0 + (size_t)d * C_;
    wv[d] = *(const float4*)(dd + pb + cb);
    zv[d] = *(const float4*)(zz + pb + cb);
    bv[d] = *(const float4*)(bbv + pb + cb);
    kv[d] = *(const float4*)(kk + pb + cb);
    rv[d] = *(const float4*)(rr + pb + cb);
    vval[d] = vv[pb + row];
  }

  for (int t0 = 0; t0 < T_; t0 += PFD) {
#pragma unroll
    for (int d = 0; d < PFD; d++) {
      const int t = t0 + d;
      const float4 w4 = wv[d], z4 = zv[d], b4 = bv[d], k4 = kv[d], r4 = rv[d];
      const float vi = vval[d];

      // prefetch step t+PFD into slot d (clamped to stay in-bounds)
      const int tp = (t + PFD < T_) ? (t + PFD) : (T_ - 1);
      const size_t pb = base0 + (size_t)tp * C_;
      wv[d] = *(const float4*)(dd + pb + cb);
      zv[d] = *(const float4*)(zz + pb + cb);
      bv[d] = *(const float4*)(bbv + pb + cb);
      kv[d] = *(const float4*)(kk + pb + cb);
      rv[d] = *(const float4*)(rr + pb + cb);
      vval[d] = vv[pb + row];

      // sa = (S . z) reduced over the 16-lane row  (tree + DPP, all VALU)
      float sa = fmaf(S1, z4.y, S0 * z4.x) + fmaf(S3, z4.w, S2 * z4.z);
      sa = row_sum16(sa);

      S0 = fmaf(S0, w4.x, fmaf(sa, b4.x, vi * k4.x));
      S1 = fmaf(S1, w4.y, fmaf(sa, b4.y, vi * k4.y));
      S2 = fmaf(S2, w4.z, fmaf(sa, b4.z, vi * k4.z));
      S3 = fmaf(S3, w4.w, fmaf(sa, b4.w, vi * k4.w));

      float yp = fmaf(S1, r4.y, S0 * r4.x) + fmaf(S3, r4.w, S2 * r4.z);
      yp = row_sum16(yp);
      if (l16 == 0) yy[base0 + (size_t)t * C_ + row] = yp;
    }
  }
}

// ---------------- GroupNorm + r_k term + g gating -> bf16 ----------------
__global__ __launch_bounds__(256) void gn_k(
    const float* __restrict__ y, const float* __restrict__ r,
    const float* __restrict__ k, const float* __restrict__ v,
    const float* __restrict__ g, const float* __restrict__ r_k,
    const float* __restrict__ ln_w, const float* __restrict__ ln_b,
    short* __restrict__ ymb) {
  const int wid = threadIdx.x >> 6;
  const int lane = threadIdx.x & 63;
  const size_t hid = (size_t)blockIdx.x * 4 + wid;
  const int h = (int)(hid % H_);
  const size_t idx = hid * 64 + lane;
  const int c = h * 64 + lane;

  const float yv = y[idx];
  const float mu = wave_sum64(yv) * (1.f / 64.f);
  const float sq = wave_sum64(yv * yv) * (1.f / 64.f);
  const float var = sq - mu * mu;
  float yn = (yv - mu) * rsqrtf(var + 0.00064f);
  yn = yn * ln_w[c] + ln_b[c];

  const float s = wave_sum64(r[idx] * k[idx] * r_k[c]);
  yn += s * v[idx];
  ymb[idx] = bf16b(yn * g[idx]);
}

// ---------------- copy ----------------
__global__ __launch_bounds__(256) void copy4_k(const float4* __restrict__ src,
                                               float4* __restrict__ dst, int n4) {
  const int i = blockIdx.x * blockDim.x + threadIdx.x;
  if (i < n4) dst[i] = src[i];
}

// ---------------- host launcher ----------------
template <bool MIX, bool BT, int EPI>
static void launch_gemm(const float* A, const float* Bm, float* Cc, int M,
                        int N, int K, const float* lam, const float* bias,
                        const float* ex1, const float* ex2, hipStream_t s) {
  dim3 grid(N / 64, M / 64), blk(256);
  hipLaunchKernelGGL((gemm_k<MIX, BT, EPI>), grid, blk, 0, s, A, Bm, Cc, M, N,
                     K, lam, bias, ex1, ex2);
}

extern "C" void kernel_launch(void* const* d_in, const int* in_sizes, int n_in,
                              void* d_out, int out_size, void* d_ws,
                              size_t ws_size, hipStream_t stream) {
  const float* x       = (const float*)d_in[0];
  const float* v_first = (const float*)d_in[1];
  const float* lam_r   = (const float*)d_in[2];
  const float* lam_w   = (const float*)d_in[3];
  const float* lam_k   = (const float*)d_in[4];
  const float* lam_v   = (const float*)d_in[5];
  const float* lam_a   = (const float*)d_in[6];
  const float* lam_g   = (const float*)d_in[7];
  const float* w_miu   = (const float*)d_in[8];
  const float* w_A     = (const float*)d_in[9];
  const float* w_B     = (const float*)d_in[10];
  const float* a_miu   = (const float*)d_in[11];
  const float* a_A     = (const float*)d_in[12];
  const float* a_B     = (const float*)d_in[13];
  const float* v_miu   = (const float*)d_in[14];
  const float* v_A     = (const float*)d_in[15];
  const float* v_B     = (const float*)d_in[16];
  const float* g_A     = (const float*)d_in[17];
  const float* g_B     = (const float*)d_in[18];
  const float* k_k     = (const float*)d_in[19];
  const float* k_a     = (const float*)d_in[20];
  const float* r_k     = (const float*)d_in[21];
  const float* W_r     = (const float*)d_in[22];
  const float* W_k     = (const float*)d_in[23];
  const float* W_v     = (const float*)d_in[24];
  const float* W_o     = (const float*)d_in[25];
  const float* ln_w    = (const float*)d_in[26];
  const float* ln_b    = (const float*)d_in[27];

  const int M = B_ * T_;            // 8192
  const size_t S = (size_t)M * C_;  // 6291456

  float* ws   = (float*)d_ws;
  float* r_   = ws + 0 * S;
  float* kbuf = ws + 1 * S;
  float* vbuf = ws + 2 * S;
  float* dec_ = ws + 3 * S;
  float* a_   = ws + 4 * S;
  float* g_   = ws + 5 * S;
  float* z_   = ws + 6 * S;
  float* bb_  = ws + 7 * S;
  float* h_   = ws + 8 * S;                       // M*128 floats
  short* wb   = (short*)(h_ + (size_t)M * 128);   // 4 bf16 weight copies
  float* out  = (float*)d_out;

  // bf16 aliases (dead fp32 slots at time of use)
  short* xr  = (short*)dec_;  // consumed before decay written
  short* xk  = (short*)a_;    // consumed before a written
  short* xv  = (short*)g_;    // consumed before g written
  short* ymb = (short*)z_;    // written after z consumed by wkv7
  const int WN = C_ * C_;     // 589824
  short* wrb = wb + 0 * (size_t)WN;
  short* wkb = wb + 1 * (size_t)WN;
  short* wvb = wb + 2 * (size_t)WN;
  short* wob = wb + 3 * (size_t)WN;

  // 1) weights -> bf16
  {
    dim3 blk(256), grid(WN / 4 / 256);
    hipLaunchKernelGGL(cvtw_k, grid, blk, 0, stream, W_r, wrb, WN / 4);
    hipLaunchKernelGGL(cvtw_k, grid, blk, 0, stream, W_k, wkb, WN / 4);
    hipLaunchKernelGGL(cvtw_k, grid, blk, 0, stream, W_v, wvb, WN / 4);
    hipLaunchKernelGGL(cvtw_k, grid, blk, 0, stream, W_o, wob, WN / 4);
  }
  // 2) mixed x -> bf16 (r/k/v lambdas)
  {
    dim3 blk(256), grid((int)(S / 4 / 256));
    hipLaunchKernelGGL(mix3_k, grid, blk, 0, stream, x, lam_r, lam_k, lam_v,
                       xr, xk, xv);
  }
  // 3) big projections via MFMA
  {
    dim3 blk(256), grid(C_ / 128, M / 128);
    hipLaunchKernelGGL(gemm_bf16_k, grid, blk, 0, stream, xr, wrb, r_, M, C_, C_);
    hipLaunchKernelGGL(gemm_bf16_k, grid, blk, 0, stream, xk, wkb, kbuf, M, C_, C_);
    hipLaunchKernelGGL(gemm_bf16_k, grid, blk, 0, stream, xv, wvb, vbuf, M, C_, C_);
  }
  // 4) v low-rank residual gate
  launch_gemm<false, false, EPI_NONE>(vbuf, v_A, h_, M, 64, C_, nullptr, nullptr, nullptr, nullptr, stream);
  launch_gemm<false, false, EPI_VMIX>(h_, v_B, vbuf, M, C_, 64, nullptr, v_miu, vbuf, v_first, stream);
  // 5) decay / a / g paths (fp32, mix fused)
  launch_gemm<true, false, EPI_TANH>(x, w_A, h_, M, 64, C_, lam_w, nullptr, nullptr, nullptr, stream);
  launch_gemm<false, false, EPI_WDECAY>(h_, w_B, dec_, M, C_, 64, nullptr, w_miu, nullptr, nullptr, stream);
  launch_gemm<true, false, EPI_NONE>(x, a_A, h_, M, 64, C_, lam_a, nullptr, nullptr, nullptr, stream);
  launch_gemm<false, false, EPI_SIGBIAS>(h_, a_B, a_, M, C_, 64, nullptr, a_miu, nullptr, nullptr, stream);
  launch_gemm<true, false, EPI_SIGMOID>(x, g_A, h_, M, 128, C_, lam_g, nullptr, nullptr, nullptr, stream);
  launch_gemm<false, false, EPI_NONE>(h_, g_B, g_, M, C_, 128, nullptr, nullptr, nullptr, nullptr, stream);
  // 6) kk prep
  {
    dim3 grid((B_ * T_ * H_) / 4), blk(256);
    hipLaunchKernelGGL(kkprep_k, grid, blk, 0, stream, kbuf, a_, k_k, k_a,
                       kbuf, z_, bb_);
  }
  // 7) recurrence -> y (a_ slot)
  {
    dim3 grid(B_ * H_ * 4), blk(256);
    hipLaunchKernelGGL(wkv7_k, grid, blk, 0, stream, r_, dec_, kbuf, vbuf, z_,
                       bb_, a_);
  }
  // 8) groupnorm + rk-term + gate -> ymb (bf16, z_ slot)
  {
    dim3 grid((B_ * T_ * H_) / 4), blk(256);
    hipLaunchKernelGGL(gn_k, grid, blk, 0, stream, a_, r_, kbuf, vbuf, g_, r_k,
                       ln_w, ln_b, ymb);
  }
  // 9) output projection via MFMA
  {
    dim3 blk(256), grid(C_ / 128, M / 128);
    hipLaunchKernelGGL(gemm_bf16_k, grid, blk, 0, stream, ymb, wob, out, M, C_, C_);
  }
  // 10) v_first passthrough
  {
    const int n4 = (int)(S / 4);
    dim3 grid((n4 + 255) / 256), blk(256);
    hipLaunchKernelGGL(copy4_k, grid, blk, 0, stream, (const float4*)v_first,
                       (float4*)(out + S), n4);
  }
}

// Round 2
// 1153.459 us; speedup vs baseline: 1.4001x; 1.2019x over previous
//
#include <hip/hip_runtime.h>
#include <hip/hip_bf16.h>
#include <math.h>

// RWKV-7 TimeMix. R5: wkv7 prefetch moved from VGPRs (168-reg array, allocator
// collapsed it) to global_load_lds double-buffered chunk staging (zero VGPR),
// + same-XCD grouping of the 4 row-quarter blocks per head for L2 dedupe.
// B=4 T=2048 C=768 H=12 N=64, LAYER_ID=1.

#define B_  4
#define T_  2048
#define C_  768
#define H_  12

typedef __attribute__((ext_vector_type(8))) short bf16x8;
typedef __attribute__((ext_vector_type(4))) float f32x4;

#define GLD16(gsrc, ldst)                                                     \
  __builtin_amdgcn_global_load_lds(                                           \
      (const __attribute__((address_space(1))) void*)(gsrc),                  \
      (__attribute__((address_space(3))) void*)(ldst), 16, 0, 0)

// ---- DPP helpers: sum across each 16-lane DPP row, all-VALU ----
template <int CTRL>
static __device__ __forceinline__ float row_ror_add(float v) {
  int t = __builtin_amdgcn_update_dpp(0, __float_as_int(v), CTRL, 0xF, 0xF, true);
  return v + __int_as_float(t);
}
static __device__ __forceinline__ float row_sum16(float v) {
  v = row_ror_add<0x128>(v);  // row_ror:8
  v = row_ror_add<0x124>(v);  // row_ror:4
  v = row_ror_add<0x122>(v);  // row_ror:2
  v = row_ror_add<0x121>(v);  // row_ror:1
  return v;                   // every lane in the 16-group holds the sum
}

static __device__ __forceinline__ float wave_sum64(float v) {
  v = row_sum16(v);
  v += __shfl_xor(v, 16);
  v += __shfl_xor(v, 32);
  return v;
}

static __device__ __forceinline__ short bf16b(float f) {
  __hip_bfloat16 h = __float2bfloat16(f);
  return *reinterpret_cast<short*>(&h);
}

// ---------------- bf16 MFMA GEMM ----------------
// C[M,N] = A[M,K](bf16) @ Bw[N,K](bf16)^T, fp32 out. 128x128 tile, BK=32.
// 4 waves in 2x2, each wave 64x64 via 4x4 grid of 16x16x32 MFMAs.
__global__ __launch_bounds__(256) void gemm_bf16_k(
    const short* __restrict__ A, const short* __restrict__ Bw,
    float* __restrict__ C, int M, int N, int K) {
  __shared__ short As[128 * 32];
  __shared__ short Bs[128 * 32];
  const int tid = threadIdx.x;
  const int wave = tid >> 6, lane = tid & 63;
  const int m0 = blockIdx.y * 128, n0 = blockIdx.x * 128;
  const int wm = (wave >> 1) * 64, wn = (wave & 1) * 64;
  const int fr = lane & 15, fk = (lane >> 4) * 8;

  f32x4 acc[4][4];
#pragma unroll
  for (int i = 0; i < 4; i++)
#pragma unroll
    for (int j = 0; j < 4; j++) acc[i][j] = (f32x4){0.f, 0.f, 0.f, 0.f};

  // staging map: thread t -> LDS short-offset 8*t == row (t>>2), col (t&3)*8
  const int srow = tid >> 2, scol = (tid & 3) * 8;
  const short* gA = A + (size_t)(m0 + srow) * K + scol;
  const short* gB = Bw + (size_t)(n0 + srow) * K + scol;
  short* lA0 = &As[wave * 512];
  short* lA1 = &As[2048 + wave * 512];
  short* lB0 = &Bs[wave * 512];
  short* lB1 = &Bs[2048 + wave * 512];

  for (int k0 = 0; k0 < K; k0 += 32) {
    GLD16(gA + k0, lA0);
    GLD16(gA + (size_t)64 * K + k0, lA1);
    GLD16(gB + k0, lB0);
    GLD16(gB + (size_t)64 * K + k0, lB1);
    __syncthreads();

    bf16x8 af[4], bf[4];
#pragma unroll
    for (int i = 0; i < 4; i++)
      af[i] = *(const bf16x8*)&As[(wm + i * 16 + fr) * 32 + fk];
#pragma unroll
    for (int j = 0; j < 4; j++)
      bf[j] = *(const bf16x8*)&Bs[(wn + j * 16 + fr) * 32 + fk];
#pragma unroll
    for (int i = 0; i < 4; i++)
#pragma unroll
      for (int j = 0; j < 4; j++)
        acc[i][j] =
            __builtin_amdgcn_mfma_f32_16x16x32_bf16(af[i], bf[j], acc[i][j], 0, 0, 0);
    __syncthreads();
  }

  // C/D layout: col = lane&15, row = (lane>>4)*4 + reg  [m89/m91 verified]
#pragma unroll
  for (int i = 0; i < 4; i++) {
    const int gm = m0 + wm + i * 16 + (lane >> 4) * 4;
#pragma unroll
    for (int j = 0; j < 4; j++) {
      const int gn = n0 + wn + j * 16 + fr;
#pragma unroll
      for (int rix = 0; rix < 4; rix++)
        C[(size_t)(gm + rix) * N + gn] = acc[i][j][rix];
    }
  }
}

// ---------------- fp32 GEMM (small paths) ----------------
enum { EPI_NONE = 0, EPI_TANH, EPI_WDECAY, EPI_SIGBIAS, EPI_SIGMOID, EPI_VMIX };

template <bool MIX, bool BT, int EPI>
__global__ __launch_bounds__(256) void gemm_k(
    const float* __restrict__ A, const float* __restrict__ Bm,
    float* __restrict__ Cc, int M, int N, int K,
    const float* __restrict__ lam, const float* __restrict__ bias,
    const float* __restrict__ ex1, const float* __restrict__ ex2) {
  __shared__ float As[64][20];
  __shared__ float Bs[64][20];
  const int tid = threadIdx.x;
  const int n0 = blockIdx.x * 64;
  const int m0 = blockIdx.y * 64;
  const int tx = tid & 15, ty = tid >> 4;

  float acc[4][4];
#pragma unroll
  for (int i = 0; i < 4; i++)
#pragma unroll
    for (int j = 0; j < 4; j++) acc[i][j] = 0.f;

  const int lm = tid >> 2;
  const int lk4 = (tid & 3) * 4;

  for (int k0 = 0; k0 < K; k0 += 16) {
    {
      const int gm = m0 + lm;
      const float* ap = A + (size_t)gm * K + k0 + lk4;
      float4 xa = *(const float4*)ap;
      if (MIX) {
        float4 xp = make_float4(0.f, 0.f, 0.f, 0.f);
        if ((gm % T_) != 0) xp = *(const float4*)(ap - K);
        const float4 l4 = *(const float4*)(lam + k0 + lk4);
        xa.x += (xp.x - xa.x) * l4.x;
        xa.y += (xp.y - xa.y) * l4.y;
        xa.z += (xp.z - xa.z) * l4.z;
        xa.w += (xp.w - xa.w) * l4.w;
      }
      *(float4*)&As[lm][lk4] = xa;
    }
    if (BT) {
      const int gn = n0 + lm;
      const float4 bv = *(const float4*)(Bm + (size_t)gn * K + k0 + lk4);
      *(float4*)&Bs[lm][lk4] = bv;
    } else {
      const int kl = tid >> 4;
      const int nl = (tid & 15) * 4;
      const float4 bv = *(const float4*)(Bm + (size_t)(k0 + kl) * N + n0 + nl);
      Bs[nl + 0][kl] = bv.x;
      Bs[nl + 1][kl] = bv.y;
      Bs[nl + 2][kl] = bv.z;
      Bs[nl + 3][kl] = bv.w;
    }
    __syncthreads();

#pragma unroll
    for (int kb = 0; kb < 16; kb += 4) {
      float a4[4][4], b4[4][4];
#pragma unroll
      for (int i = 0; i < 4; i++) {
        const float4 t = *(const float4*)&As[ty * 4 + i][kb];
        a4[i][0] = t.x; a4[i][1] = t.y; a4[i][2] = t.z; a4[i][3] = t.w;
      }
#pragma unroll
      for (int j = 0; j < 4; j++) {
        const float4 t = *(const float4*)&Bs[tx * 4 + j][kb];
        b4[j][0] = t.x; b4[j][1] = t.y; b4[j][2] = t.z; b4[j][3] = t.w;
      }
#pragma unroll
      for (int u = 0; u < 4; u++)
#pragma unroll
        for (int i = 0; i < 4; i++)
#pragma unroll
          for (int j = 0; j < 4; j++)
            acc[i][j] = fmaf(a4[i][u], b4[j][u], acc[i][j]);
    }
    __syncthreads();
  }

#pragma unroll
  for (int i = 0; i < 4; i++) {
    const int gm = m0 + ty * 4 + i;
    float res[4];
#pragma unroll
    for (int j = 0; j < 4; j++) {
      const int n = n0 + tx * 4 + j;
      float val = acc[i][j];
      if (EPI == EPI_TANH) {
        val = tanhf(val);
      } else if (EPI == EPI_WDECAY) {
        const float u = bias[n] + val;
        const float sig = 1.f / (1.f + expf(-u));
        val = expf(-0.60653065971263342f * sig);
      } else if (EPI == EPI_SIGBIAS) {
        const float u = bias[n] + val;
        val = 1.f / (1.f + expf(-u));
      } else if (EPI == EPI_SIGMOID) {
        val = 1.f / (1.f + expf(-val));
      } else if (EPI == EPI_VMIX) {
        const float u = bias[n] + val;
        const float sg = 1.f / (1.f + expf(-u));
        const size_t off = (size_t)gm * N + n;
        const float v0v = ex1[off];
        const float vf = ex2[off];
        val = v0v + (vf - v0v) * sg;
      }
      res[j] = val;
    }
    *(float4*)(Cc + (size_t)gm * N + n0 + tx * 4) =
        make_float4(res[0], res[1], res[2], res[3]);
  }
}

// ---------------- mix -> bf16 (3 lambdas) ----------------
__global__ __launch_bounds__(256) void mix3_k(
    const float* __restrict__ x, const float* __restrict__ lr,
    const float* __restrict__ lk, const float* __restrict__ lv,
    short* __restrict__ xr, short* __restrict__ xk, short* __restrict__ xv) {
  const int i = blockIdx.x * 256 + threadIdx.x;  // float4 index
  const int c4 = i % (C_ / 4);
  const int gm = i / (C_ / 4);
  const float4 xa = ((const float4*)x)[i];
  float4 xp = make_float4(0.f, 0.f, 0.f, 0.f);
  if ((gm % T_) != 0) xp = ((const float4*)x)[i - C_ / 4];
  const float4 dx = make_float4(xp.x - xa.x, xp.y - xa.y, xp.z - xa.z, xp.w - xa.w);

  const float4 l1 = ((const float4*)lr)[c4];
  const float4 l2 = ((const float4*)lk)[c4];
  const float4 l3 = ((const float4*)lv)[c4];
  short4 o1 = {bf16b(fmaf(dx.x, l1.x, xa.x)), bf16b(fmaf(dx.y, l1.y, xa.y)),
               bf16b(fmaf(dx.z, l1.z, xa.z)), bf16b(fmaf(dx.w, l1.w, xa.w))};
  short4 o2 = {bf16b(fmaf(dx.x, l2.x, xa.x)), bf16b(fmaf(dx.y, l2.y, xa.y)),
               bf16b(fmaf(dx.z, l2.z, xa.z)), bf16b(fmaf(dx.w, l2.w, xa.w))};
  short4 o3 = {bf16b(fmaf(dx.x, l3.x, xa.x)), bf16b(fmaf(dx.y, l3.y, xa.y)),
               bf16b(fmaf(dx.z, l3.z, xa.z)), bf16b(fmaf(dx.w, l3.w, xa.w))};
  ((short4*)xr)[i] = o1;
  ((short4*)xk)[i] = o2;
  ((short4*)xv)[i] = o3;
}

// ---------------- fp32 -> bf16 convert ----------------
__global__ __launch_bounds__(256) void cvtw_k(const float* __restrict__ in,
                                              short* __restrict__ out, int n4) {
  const int i = blockIdx.x * 256 + threadIdx.x;
  if (i >= n4) return;
  const float4 v = ((const float4*)in)[i];
  short4 o = {bf16b(v.x), bf16b(v.y), bf16b(v.z), bf16b(v.w)};
  ((short4*)out)[i] = o;
}

// ---------------- kk prep ----------------
__global__ __launch_bounds__(256) void kkprep_k(
    const float* __restrict__ k0, const float* __restrict__ a,
    const float* __restrict__ k_k, const float* __restrict__ k_a,
    float* __restrict__ kout, float* __restrict__ z, float* __restrict__ bb) {
  const int wid = threadIdx.x >> 6;
  const int lane = threadIdx.x & 63;
  const size_t hid = (size_t)blockIdx.x * 4 + wid;
  const int h = (int)(hid % H_);
  const size_t idx = hid * 64 + lane;
  const int c = h * 64 + lane;
  const float kv = k0[idx];
  const float av = a[idx];
  const float kk = kv * k_k[c];
  const float ss = wave_sum64(kk * kk);
  const float denom = fmaxf(sqrtf(ss), 1e-12f);
  const float kkn = kk / denom;
  z[idx] = -kkn;
  bb[idx] = kkn * av;
  kout[idx] = kv * (1.f + (av - 1.f) * k_a[c]);
}

// ---------------- WKV-7 recurrence ----------------
// R5: 192 blocks x 256 threads (4 waves). Chunked LDS double-buffer:
// global_load_lds stages CH=16 timesteps of all 6 streams (24 KB) for the
// next chunk while the serial chain consumes the current chunk from LDS with
// a 2-step-ahead register ping-pong. Zero VGPRs spent on global prefetch.
// Block remap: bh = blk % 48 puts the 4 row-quarter blocks of one head on
// one XCD (blk%8 == bh%8 under round-robin dispatch) -> L2 dedupe.
#define CH 16
#define NC (T_ / CH)
__global__ __launch_bounds__(256) void wkv7_k(
    const float* __restrict__ rr, const float* __restrict__ dd,
    const float* __restrict__ kk, const float* __restrict__ vv,
    const float* __restrict__ zz, const float* __restrict__ bbv,
    float* __restrict__ yy) {
  __shared__ float lds[2][6 * CH * 64];  // 2 x 24 KB
  const int blk = blockIdx.x;
  const int bh = blk % 48;
  const int rq = blk / 48;
  const int b = bh / H_, h = bh % H_;
  const int tid = threadIdx.x;
  const int wave = tid >> 6;
  const int l = tid & 63;
  const int l16 = l & 15;
  const int row = rq * 16 + wave * 4 + (l >> 4);
  const int cb = l16 * 4;
  const size_t btb = (size_t)b * T_;

  // staging: wave w covers timesteps [w*4, w*4+4) of the chunk for all 6
  // streams; lane l -> step (l>>4), cols (l&15)*4. LDS dest is linear.
  const size_t g0 = (btb + wave * 4 + (l >> 4)) * C_ + h * 64 + cb;
  const int dbase = wave * 256;  // floats: 4 steps * 64

#define STAGE(BUF, GOFF)                                                      \
  {                                                                           \
    float* Ld = &lds[BUF][0];                                                 \
    GLD16(dd + (GOFF), Ld + 0 * 1024 + dbase);                                \
    GLD16(zz + (GOFF), Ld + 1 * 1024 + dbase);                                \
    GLD16(bbv + (GOFF), Ld + 2 * 1024 + dbase);                               \
    GLD16(kk + (GOFF), Ld + 3 * 1024 + dbase);                                \
    GLD16(rr + (GOFF), Ld + 4 * 1024 + dbase);                                \
    GLD16(vv + (GOFF), Ld + 5 * 1024 + dbase);                                \
  }

#define LDSTEP(S_, TL_)                                                       \
  {                                                                           \
    Wf[S_] = *(const float4*)&Lb[0 * 1024 + (TL_) * 64 + cb];                 \
    Zf[S_] = *(const float4*)&Lb[1 * 1024 + (TL_) * 64 + cb];                 \
    Bf[S_] = *(const float4*)&Lb[2 * 1024 + (TL_) * 64 + cb];                 \
    Kf[S_] = *(const float4*)&Lb[3 * 1024 + (TL_) * 64 + cb];                 \
    Rf[S_] = *(const float4*)&Lb[4 * 1024 + (TL_) * 64 + cb];                 \
    Vf[S_] = Lb[5 * 1024 + (TL_) * 64 + row];                                 \
  }

  STAGE(0, g0);
  __syncthreads();

  float S0 = 0.f, S1 = 0.f, S2 = 0.f, S3 = 0.f;
  size_t gpf = g0 + (size_t)CH * C_;
  const size_t ybase = btb * C_ + h * 64 + row;

  for (int c = 0; c < NC; ++c) {
    if (c + 1 < NC) STAGE((c + 1) & 1, gpf);
    gpf += (size_t)CH * C_;
    const float* Lb = lds[c & 1];

    float4 Wf[3], Zf[3], Bf[3], Kf[3], Rf[3];
    float Vf[3];
    LDSTEP(0, 0);
    LDSTEP(1, 1);
#pragma unroll
    for (int tl = 0; tl < CH; ++tl) {
      const int sl = tl % 3;  // compile-time after unroll
      if (tl + 2 < CH) {
        const int s2 = (tl + 2) % 3;
        LDSTEP(s2, tl + 2);
      }
      const float4 w4 = Wf[sl], z4 = Zf[sl], b4 = Bf[sl], k4 = Kf[sl],
                   r4 = Rf[sl];
      const float vi = Vf[sl];

      float sa = fmaf(S1, z4.y, S0 * z4.x) + fmaf(S3, z4.w, S2 * z4.z);
      sa = row_sum16(sa);

      S0 = fmaf(S0, w4.x, fmaf(sa, b4.x, vi * k4.x));
      S1 = fmaf(S1, w4.y, fmaf(sa, b4.y, vi * k4.y));
      S2 = fmaf(S2, w4.z, fmaf(sa, b4.z, vi * k4.z));
      S3 = fmaf(S3, w4.w, fmaf(sa, b4.w, vi * k4.w));

      float yp = fmaf(S1, r4.y, S0 * r4.x) + fmaf(S3, r4.w, S2 * r4.z);
      yp = row_sum16(yp);
      if (l16 == 0) yy[ybase + (size_t)(c * CH + tl) * C_] = yp;
    }
    __syncthreads();  // implicit vmcnt(0): staging for c+1 landed; all waves
                      // done reading buf c&1 before it is restaged
  }
#undef STAGE
#undef LDSTEP
}

// ---------------- GroupNorm + r_k term + g gating -> bf16 ----------------
__global__ __launch_bounds__(256) void gn_k(
    const float* __restrict__ y, const float* __restrict__ r,
    const float* __restrict__ k, const float* __restrict__ v,
    const float* __restrict__ g, const float* __restrict__ r_k,
    const float* __restrict__ ln_w, const float* __restrict__ ln_b,
    short* __restrict__ ymb) {
  const int wid = threadIdx.x >> 6;
  const int lane = threadIdx.x & 63;
  const size_t hid = (size_t)blockIdx.x * 4 + wid;
  const int h = (int)(hid % H_);
  const size_t idx = hid * 64 + lane;
  const int c = h * 64 + lane;

  const float yv = y[idx];
  const float mu = wave_sum64(yv) * (1.f / 64.f);
  const float sq = wave_sum64(yv * yv) * (1.f / 64.f);
  const float var = sq - mu * mu;
  float yn = (yv - mu) * rsqrtf(var + 0.00064f);
  yn = yn * ln_w[c] + ln_b[c];

  const float s = wave_sum64(r[idx] * k[idx] * r_k[c]);
  yn += s * v[idx];
  ymb[idx] = bf16b(yn * g[idx]);
}

// ---------------- copy ----------------
__global__ __launch_bounds__(256) void copy4_k(const float4* __restrict__ src,
                                               float4* __restrict__ dst, int n4) {
  const int i = blockIdx.x * blockDim.x + threadIdx.x;
  if (i < n4) dst[i] = src[i];
}

// ---------------- host launcher ----------------
template <bool MIX, bool BT, int EPI>
static void launch_gemm(const float* A, const float* Bm, float* Cc, int M,
                        int N, int K, const float* lam, const float* bias,
                        const float* ex1, const float* ex2, hipStream_t s) {
  dim3 grid(N / 64, M / 64), blk(256);
  hipLaunchKernelGGL((gemm_k<MIX, BT, EPI>), grid, blk, 0, s, A, Bm, Cc, M, N,
                     K, lam, bias, ex1, ex2);
}

extern "C" void kernel_launch(void* const* d_in, const int* in_sizes, int n_in,
                              void* d_out, int out_size, void* d_ws,
                              size_t ws_size, hipStream_t stream) {
  const float* x       = (const float*)d_in[0];
  const float* v_first = (const float*)d_in[1];
  const float* lam_r   = (const float*)d_in[2];
  const float* lam_w   = (const float*)d_in[3];
  const float* lam_k   = (const float*)d_in[4];
  const float* lam_v   = (const float*)d_in[5];
  const float* lam_a   = (const float*)d_in[6];
  const float* lam_g   = (const float*)d_in[7];
  const float* w_miu   = (const float*)d_in[8];
  const float* w_A     = (const float*)d_in[9];
  const float* w_B     = (const float*)d_in[10];
  const float* a_miu   = (const float*)d_in[11];
  const float* a_A     = (const float*)d_in[12];
  const float* a_B     = (const float*)d_in[13];
  const float* v_miu   = (const float*)d_in[14];
  const float* v_A     = (const float*)d_in[15];
  const float* v_B     = (const float*)d_in[16];
  const float* g_A     = (const float*)d_in[17];
  const float* g_B     = (const float*)d_in[18];
  const float* k_k     = (const float*)d_in[19];
  const float* k_a     = (const float*)d_in[20];
  const float* r_k     = (const float*)d_in[21];
  const float* W_r     = (const float*)d_in[22];
  const float* W_k     = (const float*)d_in[23];
  const float* W_v     = (const float*)d_in[24];
  const float* W_o     = (const float*)d_in[25];
  const float* ln_w    = (const float*)d_in[26];
  const float* ln_b    = (const float*)d_in[27];

  const int M = B_ * T_;            // 8192
  const size_t S = (size_t)M * C_;  // 6291456

  float* ws   = (float*)d_ws;
  float* r_   = ws + 0 * S;
  float* kbuf = ws + 1 * S;
  float* vbuf = ws + 2 * S;
  float* dec_ = ws + 3 * S;
  float* a_   = ws + 4 * S;
  float* g_   = ws + 5 * S;
  float* z_   = ws + 6 * S;
  float* bb_  = ws + 7 * S;
  float* h_   = ws + 8 * S;                       // M*128 floats
  short* wb   = (short*)(h_ + (size_t)M * 128);   // 4 bf16 weight copies
  float* out  = (float*)d_out;

  // bf16 aliases (dead fp32 slots at time of use)
  short* xr  = (short*)dec_;  // consumed before decay written
  short* xk  = (short*)a_;    // consumed before a written
  short* xv  = (short*)g_;    // consumed before g written
  short* ymb = (short*)z_;    // written after z consumed by wkv7
  const int WN = C_ * C_;     // 589824
  short* wrb = wb + 0 * (size_t)WN;
  short* wkb = wb + 1 * (size_t)WN;
  short* wvb = wb + 2 * (size_t)WN;
  short* wob = wb + 3 * (size_t)WN;

  // 1) weights -> bf16
  {
    dim3 blk(256), grid(WN / 4 / 256);
    hipLaunchKernelGGL(cvtw_k, grid, blk, 0, stream, W_r, wrb, WN / 4);
    hipLaunchKernelGGL(cvtw_k, grid, blk, 0, stream, W_k, wkb, WN / 4);
    hipLaunchKernelGGL(cvtw_k, grid, blk, 0, stream, W_v, wvb, WN / 4);
    hipLaunchKernelGGL(cvtw_k, grid, blk, 0, stream, W_o, wob, WN / 4);
  }
  // 2) mixed x -> bf16 (r/k/v lambdas)
  {
    dim3 blk(256), grid((int)(S / 4 / 256));
    hipLaunchKernelGGL(mix3_k, grid, blk, 0, stream, x, lam_r, lam_k, lam_v,
                       xr, xk, xv);
  }
  // 3) big projections via MFMA
  {
    dim3 blk(256), grid(C_ / 128, M / 128);
    hipLaunchKernelGGL(gemm_bf16_k, grid, blk, 0, stream, xr, wrb, r_, M, C_, C_);
    hipLaunchKernelGGL(gemm_bf16_k, grid, blk, 0, stream, xk, wkb, kbuf, M, C_, C_);
    hipLaunchKernelGGL(gemm_bf16_k, grid, blk, 0, stream, xv, wvb, vbuf, M, C_, C_);
  }
  // 4) v low-rank residual gate
  launch_gemm<false, false, EPI_NONE>(vbuf, v_A, h_, M, 64, C_, nullptr, nullptr, nullptr, nullptr, stream);
  launch_gemm<false, false, EPI_VMIX>(h_, v_B, vbuf, M, C_, 64, nullptr, v_miu, vbuf, v_first, stream);
  // 5) decay / a / g paths (fp32, mix fused)
  launch_gemm<true, false, EPI_TANH>(x, w_A, h_, M, 64, C_, lam_w, nullptr, nullptr, nullptr, stream);
  launch_gemm<false, false, EPI_WDECAY>(h_, w_B, dec_, M, C_, 64, nullptr, w_miu, nullptr, nullptr, stream);
  launch_gemm<true, false, EPI_NONE>(x, a_A, h_, M, 64, C_, lam_a, nullptr, nullptr, nullptr, stream);
  launch_gemm<false, false, EPI_SIGBIAS>(h_, a_B, a_, M, C_, 64, nullptr, a_miu, nullptr, nullptr, stream);
  launch_gemm<true, false, EPI_SIGMOID>(x, g_A, h_, M, 128, C_, lam_g, nullptr, nullptr, nullptr, stream);
  launch_gemm<false, false, EPI_NONE>(h_, g_B, g_, M, C_, 128, nullptr, nullptr, nullptr, nullptr, stream);
  // 6) kk prep
  {
    dim3 grid((B_ * T_ * H_) / 4), blk(256);
    hipLaunchKernelGGL(kkprep_k, grid, blk, 0, stream, kbuf, a_, k_k, k_a,
                       kbuf, z_, bb_);
  }
  // 7) recurrence -> y (a_ slot)
  {
    dim3 grid(B_ * H_ * 4), blk(256);
    hipLaunchKernelGGL(wkv7_k, grid, blk, 0, stream, r_, dec_, kbuf, vbuf, z_,
                       bb_, a_);
  }
  // 8) groupnorm + rk-term + gate -> ymb (bf16, z_ slot)
  {
    dim3 grid((B_ * T_ * H_) / 4), blk(256);
    hipLaunchKernelGGL(gn_k, grid, blk, 0, stream, a_, r_, kbuf, vbuf, g_, r_k,
                       ln_w, ln_b, ymb);
  }
  // 9) output projection via MFMA
  {
    dim3 blk(256), grid(C_ / 128, M / 128);
    hipLaunchKernelGGL(gemm_bf16_k, grid, blk, 0, stream, ymb, wob, out, M, C_, C_);
  }
  // 10) v_first passthrough
  {
    const int n4 = (int)(S / 4);
    dim3 grid((n4 + 255) / 256), blk(256);
    hipLaunchKernelGGL(copy4_k, grid, blk, 0, stream, (const float4*)v_first,
                       (float4*)(out + S), n4);
  }
}